// Round 20
// baseline (155.799 us; speedup 1.0000x reference)
//
#include <hip/hip_runtime.h>

typedef __attribute__((ext_vector_type(4))) float f32x4;
typedef __attribute__((ext_vector_type(16))) float f32x16;
typedef __attribute__((ext_vector_type(8))) short s16x8;

#define GLDS(gsrc, ldst) \
  __builtin_amdgcn_global_load_lds((const __attribute__((address_space(1))) void*)(gsrc), \
                                   (__attribute__((address_space(3))) void*)(ldst), 16, 0, 0)

__device__ __forceinline__ ushort f2bf(float f) {
  union { float f; unsigned u; } x; x.f = f;
  unsigned r = (x.u + 0x7FFFu + ((x.u >> 16) & 1u)) >> 16;
  return (ushort)r;
}

__device__ __forceinline__ float fexp2(float x) {
  float r;
  asm("v_exp_f32 %0, %1" : "=v"(r) : "v"(x));
  return r;
}

__device__ __forceinline__ uint cvtpk(float a, float b) {
  uint r;
  asm("v_cvt_pk_bf16_f32 %0, %1, %2" : "=v"(r) : "v"(a), "v"(b));
  return r;
}

__device__ __forceinline__ s16x8 mk_frag(uint x0, uint x1, uint x2, uint x3) {
  union { uint u[4]; s16x8 v; } t;
  t.u[0] = x0; t.u[1] = x1; t.u[2] = x2; t.u[3] = x3;
  return t.v;
}

// ---------------- fused cast f32 -> bf16 (x, wq, wk, wv, wo) ----------------
__global__ __launch_bounds__(256) void castall(
    const float* __restrict__ x, const float* __restrict__ wq, const float* __restrict__ wk,
    const float* __restrict__ wv, const float* __restrict__ wo,
    ushort* __restrict__ xb, ushort* __restrict__ wqkvb, ushort* __restrict__ wob) {
  int bid = blockIdx.x;
  const float* in; ushort* op;
  if (bid < 8192)       { in = x;  op = xb; }
  else if (bid < 9216)  { in = wq; op = wqkvb;           bid -= 8192; }
  else if (bid < 10240) { in = wk; op = wqkvb + 1048576; bid -= 9216; }
  else if (bid < 11264) { in = wv; op = wqkvb + 2097152; bid -= 10240; }
  else                  { in = wo; op = wob;             bid -= 11264; }
  int i = (bid * 256 + threadIdx.x) * 4;
  float4 v = *(const float4*)(in + i);
  ushort4 r;
  r.x = f2bf(v.x); r.y = f2bf(v.y); r.z = f2bf(v.z); r.w = f2bf(v.w);
  *(ushort4*)(op + i) = r;
}

// ---------------- GEMM 128x256, BK=64, 8 waves, triple-buffered (r5 proven) ----------------
template<int OUTBF16>
__global__ __launch_bounds__(512, 2) void gemm256(
    const ushort* __restrict__ A, const ushort* __restrict__ Bt,
    const float* __restrict__ bias0, const float* __restrict__ bias1,
    const float* __restrict__ bias2,
    void* __restrict__ Cout, int M, int N, int K, int nxn)
{
  __shared__ __align__(16) ushort lds[73728];
  const int tid = threadIdx.x;
  const int w = tid >> 6, lane = tid & 63;
  const int lrow = lane & 15, lg = lane >> 4;
  const int wm = w >> 2, wn = w & 3;
  const int cpx = gridDim.x >> 3;
  const int wgid = ((int)blockIdx.x & 7) * cpx + ((int)blockIdx.x >> 3);
  const int mblk = (wgid / nxn) * 128;
  const int nblk = (wgid % nxn) * 256;
  const int NT = K >> 6;

  const int srow = tid >> 3;
  const int scol = 8 * ((tid & 7) ^ (srow & 7));
  const ushort* Abase = A + (size_t)(mblk + srow) * K + scol;
  const ushort* Bbase = Bt + (size_t)(nblk + srow) * K + scol;
  const size_t rstep = (size_t)64 * K;
  const int dA = w * 512;
  const int dB = 8192 + w * 512;

#define STAGE_A(p, bf) { \
    GLDS((p),         &lds[(bf) + dA]); \
    GLDS((p) + rstep, &lds[(bf) + dA + 4096]); }
#define STAGE_B(p, bf) { \
    GLDS((p),             &lds[(bf) + dB]); \
    GLDS((p) + rstep,     &lds[(bf) + dB + 4096]); \
    GLDS((p) + 2 * rstep, &lds[(bf) + dB + 8192]); \
    GLDS((p) + 3 * rstep, &lds[(bf) + dB + 12288]); }

  const int laneA0 = (wm * 64 + lrow) * 64 + ((lg ^ (lrow & 7)) << 3);
  const int laneA1 = (wm * 64 + lrow) * 64 + (((4 + lg) ^ (lrow & 7)) << 3);
  const int laneB0 = 8192 + (wn * 64 + lrow) * 64 + ((lg ^ (lrow & 7)) << 3);
  const int laneB1 = 8192 + (wn * 64 + lrow) * 64 + (((4 + lg) ^ (lrow & 7)) << 3);

  const f32x4 zero = {0.f, 0.f, 0.f, 0.f};
  f32x4 acc[4][4];
#pragma unroll
  for (int m = 0; m < 4; m++)
#pragma unroll
    for (int n = 0; n < 4; n++) acc[m][n] = zero;

  STAGE_A(Abase, 0); STAGE_B(Bbase, 0);
  if (NT > 1) { STAGE_A(Abase + 64, 24576); STAGE_B(Bbase + 64, 24576); }

  const ushort* aP = Abase + 128;
  const ushort* bP = Bbase + 128;
  int bb = 0, bbS = 49152;

  for (int t = 0; t < NT; ++t) {
    if (t < NT - 1) { asm volatile("s_waitcnt vmcnt(6)" ::: "memory"); }
    else            { asm volatile("s_waitcnt vmcnt(0)" ::: "memory"); }
    __builtin_amdgcn_s_barrier();
    const int pA0 = bb + laneA0, pA1 = bb + laneA1;
    const int pB0 = bb + laneB0, pB1 = bb + laneB1;
    const bool pf = (t + 2 < NT);

    if (pf) STAGE_A(aP, bbS);
    {
      s16x8 af[4], bf_[4];
#pragma unroll
      for (int m = 0; m < 4; m++) af[m] = *(const s16x8*)&lds[pA0 + m * 1024];
#pragma unroll
      for (int n = 0; n < 4; n++) bf_[n] = *(const s16x8*)&lds[pB0 + n * 1024];
      __builtin_amdgcn_s_setprio(1);
#pragma unroll
      for (int m = 0; m < 4; m++)
#pragma unroll
        for (int n = 0; n < 4; n++)
          acc[m][n] = __builtin_amdgcn_mfma_f32_16x16x32_bf16(af[m], bf_[n], acc[m][n], 0, 0, 0);
      __builtin_amdgcn_s_setprio(0);
    }
    if (pf) STAGE_B(bP, bbS);
    {
      s16x8 af[4], bf_[4];
#pragma unroll
      for (int m = 0; m < 4; m++) af[m] = *(const s16x8*)&lds[pA1 + m * 1024];
#pragma unroll
      for (int n = 0; n < 4; n++) bf_[n] = *(const s16x8*)&lds[pB1 + n * 1024];
      __builtin_amdgcn_s_setprio(1);
#pragma unroll
      for (int m = 0; m < 4; m++)
#pragma unroll
        for (int n = 0; n < 4; n++)
          acc[m][n] = __builtin_amdgcn_mfma_f32_16x16x32_bf16(af[m], bf_[n], acc[m][n], 0, 0, 0);
      __builtin_amdgcn_s_setprio(0);
    }
    if (pf) { aP += 64; bP += 64; }
    bb  = (bb  == 49152) ? 0 : bb + 24576;
    bbS = (bbS == 49152) ? 0 : bbS + 24576;
  }
#undef STAGE_A
#undef STAGE_B

  float bias_n[4];
#pragma unroll
  for (int n = 0; n < 4; n++) {
    const int col = nblk + wn * 64 + n * 16 + lrow;
    if (bias1) bias_n[n] = (col < 1024) ? bias0[col]
                          : (col < 2048 ? bias1[col - 1024] : bias2[col - 2048]);
    else bias_n[n] = bias0[col];
  }

  __syncthreads();

  if (OUTBF16) {
    ushort* Ct = lds;
#pragma unroll
    for (int m = 0; m < 4; m++)
#pragma unroll
      for (int n = 0; n < 4; n++)
#pragma unroll
        for (int i = 0; i < 4; i++)
          Ct[(wm * 64 + m * 16 + 4 * lg + i) * 256 + wn * 64 + n * 16 + lrow] =
              f2bf(acc[m][n][i] + bias_n[n]);
    __syncthreads();
    ushort* Cg = (ushort*)Cout;
#pragma unroll
    for (int r = 0; r < 8; r++) {
      const int row = r * 16 + (tid >> 5);
      const int col = (tid & 31) * 8;
      *(s16x8*)&Cg[(size_t)(mblk + row) * N + nblk + col] = *(const s16x8*)&lds[r * 4096 + tid * 8];
    }
  } else {
    float* Cf = (float*)lds;
#pragma unroll
    for (int m = 0; m < 4; m++)
#pragma unroll
      for (int n = 0; n < 4; n++)
#pragma unroll
        for (int i = 0; i < 4; i++)
          Cf[(wm * 64 + m * 16 + 4 * lg + i) * 256 + wn * 64 + n * 16 + lrow] =
              acc[m][n][i] + bias_n[n];
    __syncthreads();
    float* Cg = (float*)Cout;
#pragma unroll
    for (int r = 0; r < 16; r++) {
      const int row = r * 8 + (tid >> 6);
      const int col = (tid & 63) * 4;
      *(float4*)&Cg[(size_t)(mblk + row) * N + nblk + col] = *(const float4*)&Cf[r * 2048 + tid * 4];
    }
  }
}

// ---------------- attention: 128-q blocks, 128-kv double-tiles (1 barrier / 128 rows) ----------------
// Two 64-row halves per iteration reuse the verified per-tile math (kvh = kv + 64*s).
// Wait math: at iter-t wait, newest outstanding = V(t+1)x4 -> vmcnt(4) drains K(t);
// K(t+1) issued post-barrier gets a full double-tile of compute to land.
__global__ __launch_bounds__(256, 2) void attn_kernel(const ushort* __restrict__ qkv,
                                                      ushort* __restrict__ outp,
                                                      float* __restrict__ oPart,
                                                      float* __restrict__ mPart,
                                                      float* __restrict__ lPart)
{
  __shared__ __align__(16) ushort Ks[2][2][4096];
  __shared__ __align__(16) ushort Vt[2][2][4096];

  const int tid = threadIdx.x;
  const int w = tid >> 6, lane = tid & 63;
  const int lq = lane & 31, hi = lane >> 5;
  const float NINF = -__builtin_inff();

  const int bid = (blockIdx.x & 7) * 184 + (blockIdx.x >> 3);
  int h, b, bx, kv_lo, kv_hi, chunk = 0;
  bool isGlobal;
  if (bid < 512) {
    isGlobal = true; h = 0;
    chunk = bid >> 6;
    int qb = bid & 63;
    b = qb >> 4; bx = qb & 15;
    kv_lo = chunk * 256; kv_hi = kv_lo + 256;
  } else {
    isGlobal = false;
    int t = bid - 512;
    h = 1 + (t >> 6);
    int qb = t & 63;
    b = qb >> 4; bx = qb & 15;
    kv_lo = bx * 128 - 128; if (kv_lo < 0) kv_lo = 0;
    kv_hi = bx * 128 + 256; if (kv_hi > 2048) kv_hi = 2048;
  }
  const int q0blk = bx * 128;
  const int qw = q0blk + 32 * w;
  const int q_abs = qw + lq;
  const ushort* Qp = qkv + (size_t)b * 2048 * 3072 + h * 64;
  const ushort* Kp = Qp + 1024;
  const ushort* Vp = Qp + 2048;

  s16x8 qf[4];
#pragma unroll
  for (int c = 0; c < 4; c++)
    qf[c] = *(const s16x8*)(Qp + (size_t)q_abs * 3072 + 16 * c + 8 * hi);

  f32x16 o0, o1;
#pragma unroll
  for (int r = 0; r < 16; r++) { o0[r] = 0.f; o1[r] = 0.f; }
  float mrun = -3e38f, lsum = 0.f;
  const float SCL = 0.18033688011112042f;  // 1/8 * log2(e)

  const int kg = lane >> 3;
  const int kswz = 8 * ((lane & 7) ^ kg);
  const int krow0 = 16 * w + kg;
  const int vsp = tid >> 3;
  const int vsg = tid & 7;

  // prologue: V(t0) 4 rows -> regs; K(t0) both halves -> Ks[0]
  const ushort* vr0 = Vp + (size_t)(kv_lo + 2 * vsp) * 3072 + 8 * vsg;
  s16x8 v0 = *(const s16x8*)vr0;
  s16x8 v1 = *(const s16x8*)(vr0 + 3072);
  s16x8 v2 = *(const s16x8*)(vr0 + 196608);          // +64 rows
  s16x8 v3 = *(const s16x8*)(vr0 + 196608 + 3072);
  GLDS(Kp + (size_t)(kv_lo + krow0) * 3072 + kswz,          &Ks[0][0][(2 * w) * 512]);
  GLDS(Kp + (size_t)(kv_lo + krow0 + 8) * 3072 + kswz,      &Ks[0][0][(2 * w + 1) * 512]);
  GLDS(Kp + (size_t)(kv_lo + 64 + krow0) * 3072 + kswz,     &Ks[0][1][(2 * w) * 512]);
  GLDS(Kp + (size_t)(kv_lo + 64 + krow0 + 8) * 3072 + kswz, &Ks[0][1][(2 * w + 1) * 512]);

  int buf = 0;
  for (int kv = kv_lo; kv < kv_hi; kv += 128) {
    const bool hasNext = (kv + 128 < kv_hi);

    s16x8 vn0, vn1, vn2, vn3;
    if (hasNext) {
      const ushort* vr = Vp + (size_t)(kv + 128 + 2 * vsp) * 3072 + 8 * vsg;
      vn0 = *(const s16x8*)vr;
      vn1 = *(const s16x8*)(vr + 3072);
      vn2 = *(const s16x8*)(vr + 196608);
      vn3 = *(const s16x8*)(vr + 196608 + 3072);
    }

    // Vt transpose-writes, both halves
#pragma unroll
    for (int j = 0; j < 8; j++) {
      const int d = 8 * vsg + j;
      const int sl = ((vsp >> 2) ^ j ^ vsg) & 7;
      const int a0 = d * 64 + sl * 8 + ((2 * vsp) & 7);
      *(uint*)&Vt[buf][0][a0] = (uint)(ushort)v0[j] | ((uint)(ushort)v1[j] << 16);
      *(uint*)&Vt[buf][1][a0] = (uint)(ushort)v2[j] | ((uint)(ushort)v3[j] << 16);
    }
    if (hasNext) asm volatile("s_waitcnt vmcnt(4)" ::: "memory");
    else         asm volatile("s_waitcnt vmcnt(0)" ::: "memory");
    asm volatile("s_waitcnt lgkmcnt(0)" ::: "memory");
    __builtin_amdgcn_s_barrier();
    if (hasNext) {
      GLDS(Kp + (size_t)(kv + 128 + krow0) * 3072 + kswz,          &Ks[buf ^ 1][0][(2 * w) * 512]);
      GLDS(Kp + (size_t)(kv + 128 + krow0 + 8) * 3072 + kswz,      &Ks[buf ^ 1][0][(2 * w + 1) * 512]);
      GLDS(Kp + (size_t)(kv + 192 + krow0) * 3072 + kswz,          &Ks[buf ^ 1][1][(2 * w) * 512]);
      GLDS(Kp + (size_t)(kv + 192 + krow0 + 8) * 3072 + kswz,      &Ks[buf ^ 1][1][(2 * w + 1) * 512]);
    }

#pragma unroll
    for (int s = 0; s < 2; s++) {
      const int kvh = kv + 64 * s;
      const bool active = isGlobal || ((kvh + 63 >= qw - 128) && (kvh <= qw + 159));
      const bool needMask = !isGlobal && active && ((kvh < qw - 97) || (kvh > qw + 65));
      if (!active) continue;

      f32x16 s0, s1;
#pragma unroll
      for (int r = 0; r < 16; r++) { s0[r] = 0.f; s1[r] = 0.f; }
      __builtin_amdgcn_s_setprio(1);
#pragma unroll
      for (int c = 0; c < 4; c++) {
        const int gx = ((2 * c + hi) ^ (lq & 7)) << 3;
        s16x8 kf0 = *(const s16x8*)&Ks[buf][s][lq * 64 + gx];
        s16x8 kf1 = *(const s16x8*)&Ks[buf][s][(32 + lq) * 64 + gx];
        s0 = __builtin_amdgcn_mfma_f32_32x32x16_bf16(kf0, qf[c], s0, 0, 0, 0);
        s1 = __builtin_amdgcn_mfma_f32_32x32x16_bf16(kf1, qf[c], s1, 0, 0, 0);
      }
      __builtin_amdgcn_s_setprio(0);

      float rm = NINF;
      if (needMask) {
#pragma unroll
        for (int r = 0; r < 16; r++) {
          const int kvr = kvh + (r & 3) + 8 * (r >> 2) + 4 * hi;
          const int dq0 = q_abs - kvr;
          s0[r] = (dq0 <= 128 && dq0 >= -128) ? s0[r] : NINF;
          const int dq1 = dq0 - 32;
          s1[r] = (dq1 <= 128 && dq1 >= -128) ? s1[r] : NINF;
          rm = fmaxf(rm, fmaxf(s0[r], s1[r]));
        }
      } else {
#pragma unroll
        for (int r = 0; r < 16; r++) rm = fmaxf(rm, fmaxf(s0[r], s1[r]));
      }
      rm = fmaxf(rm, __shfl_xor(rm, 32)) * SCL;

      if (!__all(rm <= mrun + 8.f)) {
        float mnew = fmaxf(mrun, rm);
        float alpha = fexp2(mrun - mnew);
        mrun = mnew;
        lsum *= alpha;
#pragma unroll
        for (int r = 0; r < 16; r++) {
          float av = __shfl(alpha, (r & 3) + 8 * (r >> 2) + 4 * hi);
          o0[r] *= av; o1[r] *= av;
        }
      }

      float rs = 0.f;
#pragma unroll
      for (int r = 0; r < 16; r++) {
        s0[r] = fexp2(__builtin_fmaf(s0[r], SCL, -mrun)); rs += s0[r];
        s1[r] = fexp2(__builtin_fmaf(s1[r], SCL, -mrun)); rs += s1[r];
      }
      rs += __shfl_xor(rs, 32);
      lsum += rs;

#pragma unroll
      for (int cc = 0; cc < 4; cc++) {
        uint x0, x1, x2, x3;
        if (cc == 0) { x0 = cvtpk(s0[0], s0[1]);  x1 = cvtpk(s0[2], s0[3]);
                       x2 = cvtpk(s0[4], s0[5]);  x3 = cvtpk(s0[6], s0[7]); }
        else if (cc == 1) { x0 = cvtpk(s0[8], s0[9]);   x1 = cvtpk(s0[10], s0[11]);
                            x2 = cvtpk(s0[12], s0[13]); x3 = cvtpk(s0[14], s0[15]); }
        else if (cc == 2) { x0 = cvtpk(s1[0], s1[1]);  x1 = cvtpk(s1[2], s1[3]);
                            x2 = cvtpk(s1[4], s1[5]);  x3 = cvtpk(s1[6], s1[7]); }
        else { x0 = cvtpk(s1[8], s1[9]);   x1 = cvtpk(s1[10], s1[11]);
               x2 = cvtpk(s1[12], s1[13]); x3 = cvtpk(s1[14], s1[15]); }
        uint t0 = hi ? x0 : x2;
        uint t1 = hi ? x1 : x3;
        uint r0 = __shfl_xor(t0, 32);
        uint r1 = __shfl_xor(t1, 32);
        uint w0 = hi ? r0 : x0;
        uint w1 = hi ? r1 : x1;
        uint w2 = hi ? x2 : r0;
        uint w3 = hi ? x3 : r1;
        s16x8 pa = mk_frag(w0, w1, w2, w3);
        __builtin_amdgcn_s_setprio(1);
#pragma unroll
        for (int db = 0; db < 2; db++) {
          const int d = 32 * db + lq;
          s16x8 vf = *(const s16x8*)&Vt[buf][s][d * 64 +
              ((((2 * cc + hi) ^ (d & 7) ^ (d >> 3)) & 7) << 3)];
          if (db == 0) o0 = __builtin_amdgcn_mfma_f32_32x32x16_bf16(pa, vf, o0, 0, 0, 0);
          else         o1 = __builtin_amdgcn_mfma_f32_32x32x16_bf16(pa, vf, o1, 0, 0, 0);
        }
        __builtin_amdgcn_s_setprio(0);
      }
    }

    v0 = vn0; v1 = vn1; v2 = vn2; v3 = vn3;
    buf ^= 1;
  }

  if (isGlobal) {
    const size_t rq = (size_t)(chunk * 4 + b) * 2048 + qw;
    if (hi == 0) {
      mPart[rq + lq] = mrun;
      lPart[rq + lq] = lsum;
    }
#pragma unroll
    for (int r = 0; r < 16; r++) {
      const int qr = (r & 3) + 8 * (r >> 2) + 4 * hi;
      oPart[(rq + qr) * 64 + lq]      = o0[r];
      oPart[(rq + qr) * 64 + 32 + lq] = o1[r];
    }
  } else {
    float linv = 1.f / lsum;
#pragma unroll
    for (int r = 0; r < 16; r++) {
      const int qr = (r & 3) + 8 * (r >> 2) + 4 * hi;
      float iv = __shfl(linv, qr);
      size_t orow = (size_t)(b * 2048 + qw + qr) * 1024 + h * 64;
      outp[orow + lq]      = f2bf(o0[r] * iv);
      outp[orow + 32 + lq] = f2bf(o1[r] * iv);
    }
  }
}

// ---------------- combine global-head partials ----------------
__global__ __launch_bounds__(256) void combine_kernel(const float* __restrict__ oPart,
                                                      const float* __restrict__ mPart,
                                                      const float* __restrict__ lPart,
                                                      ushort* __restrict__ attno) {
  const int tid = threadIdx.x;
  const int row = blockIdx.x * 64 + (tid >> 2);
  const int d0 = (tid & 3) * 16;
  float m[8], l[8], M = -3e38f;
#pragma unroll
  for (int p = 0; p < 8; p++) {
    m[p] = mPart[p * 8192 + row];
    l[p] = lPart[p * 8192 + row];
    M = fmaxf(M, m[p]);
  }
  float L = 0.f, wgt[8];
#pragma unroll
  for (int p = 0; p < 8; p++) { wgt[p] = fexp2(m[p] - M); L += wgt[p] * l[p]; }
  float inv = 1.f / L;
  float acc[16];
#pragma unroll
  for (int j = 0; j < 16; j++) acc[j] = 0.f;
#pragma unroll
  for (int p = 0; p < 8; p++) {
    const float* op = oPart + ((size_t)p * 8192 + row) * 64 + d0;
    float wv = wgt[p];
#pragma unroll
    for (int j = 0; j < 16; j += 4) {
      float4 v = *(const float4*)(op + j);
      acc[j]     += wv * v.x; acc[j + 1] += wv * v.y;
      acc[j + 2] += wv * v.z; acc[j + 3] += wv * v.w;
    }
  }
  ushort* dst = attno + (size_t)row * 1024 + d0;
#pragma unroll
  for (int j = 0; j < 16; j++) dst[j] = f2bf(acc[j] * inv);
}

// ---------------- launch ----------------
extern "C" void kernel_launch(void* const* d_in, const int* in_sizes, int n_in,
                              void* d_out, int out_size, void* d_ws, size_t ws_size,
                              hipStream_t stream) {
  const float* x  = (const float*)d_in[0];
  const float* wq = (const float*)d_in[1];
  const float* bq = (const float*)d_in[2];
  const float* wk = (const float*)d_in[3];
  const float* bk = (const float*)d_in[4];
  const float* wv = (const float*)d_in[5];
  const float* bv = (const float*)d_in[6];
  const float* wo = (const float*)d_in[7];
  const float* bo = (const float*)d_in[8];

  char* ws = (char*)d_ws;
  ushort* xb    = (ushort*)(ws);                 // 8192x1024 bf16 = 16 MB
  ushort* wqkvb = (ushort*)(ws + 16777216);      // 3072x1024 bf16 =  6 MB
  ushort* wob   = (ushort*)(ws + 23068672);      // 1024x1024 bf16 =  2 MB
  ushort* qkvb  = (ushort*)(ws + 25165824);      // 8192x3072 bf16 = 48 MB
  ushort* attno = (ushort*)(ws + 75497472);      // 8192x1024 bf16 = 16 MB
  float* oPart = (float*)(ws);                   // 8x8192x64 f32 = 16 MB (over xb)
  float* mPart = (float*)(ws + 16777216);
  float* lPart = (float*)(ws + 16777216 + 262144);

  castall<<<12288, 256, 0, stream>>>(x, wq, wk, wv, wo, xb, wqkvb, wob);

  gemm256<1><<<768, 512, 0, stream>>>(xb, wqkvb, bq, bk, bv,
                                      (void*)qkvb, 8192, 3072, 1024, 12);

  attn_kernel<<<1472, 256, 0, stream>>>(qkvb, attno, oPart, mPart, lPart);
  combine_kernel<<<128, 256, 0, stream>>>(oPart, mPart, lPart, attno);

  gemm256<0><<<256, 512, 0, stream>>>(attno, wob, bo, nullptr, nullptr,
                                      (void*)d_out, 8192, 1024, 1024, 4);
}

// Round 21
// 153.093 us; speedup vs baseline: 1.0177x; 1.0177x over previous
//
#include <hip/hip_runtime.h>

typedef __attribute__((ext_vector_type(4))) float f32x4;
typedef __attribute__((ext_vector_type(16))) float f32x16;
typedef __attribute__((ext_vector_type(8))) short s16x8;

#define GLDS(gsrc, ldst) \
  __builtin_amdgcn_global_load_lds((const __attribute__((address_space(1))) void*)(gsrc), \
                                   (__attribute__((address_space(3))) void*)(ldst), 16, 0, 0)

__device__ __forceinline__ ushort f2bf(float f) {
  union { float f; unsigned u; } x; x.f = f;
  unsigned r = (x.u + 0x7FFFu + ((x.u >> 16) & 1u)) >> 16;
  return (ushort)r;
}

__device__ __forceinline__ float fexp2(float x) {
  float r;
  asm("v_exp_f32 %0, %1" : "=v"(r) : "v"(x));
  return r;
}

__device__ __forceinline__ uint cvtpk(float a, float b) {
  uint r;
  asm("v_cvt_pk_bf16_f32 %0, %1, %2" : "=v"(r) : "v"(a), "v"(b));
  return r;
}

__device__ __forceinline__ s16x8 mk_frag(uint x0, uint x1, uint x2, uint x3) {
  union { uint u[4]; s16x8 v; } t;
  t.u[0] = x0; t.u[1] = x1; t.u[2] = x2; t.u[3] = x3;
  return t.v;
}

// ---------------- fused cast f32 -> bf16 (x, wq, wk, wv, wo) ----------------
__global__ __launch_bounds__(256) void castall(
    const float* __restrict__ x, const float* __restrict__ wq, const float* __restrict__ wk,
    const float* __restrict__ wv, const float* __restrict__ wo,
    ushort* __restrict__ xb, ushort* __restrict__ wqkvb, ushort* __restrict__ wob) {
  int bid = blockIdx.x;
  const float* in; ushort* op;
  if (bid < 8192)       { in = x;  op = xb; }
  else if (bid < 9216)  { in = wq; op = wqkvb;           bid -= 8192; }
  else if (bid < 10240) { in = wk; op = wqkvb + 1048576; bid -= 9216; }
  else if (bid < 11264) { in = wv; op = wqkvb + 2097152; bid -= 10240; }
  else                  { in = wo; op = wob;             bid -= 11264; }
  int i = (bid * 256 + threadIdx.x) * 4;
  float4 v = *(const float4*)(in + i);
  ushort4 r;
  r.x = f2bf(v.x); r.y = f2bf(v.y); r.z = f2bf(v.z); r.w = f2bf(v.w);
  *(ushort4*)(op + i) = r;
}

// ---------------- GEMM 128x256, BK=64, 8 waves, triple-buffered (r5 proven) ----------------
template<int OUTBF16>
__global__ __launch_bounds__(512, 2) void gemm256(
    const ushort* __restrict__ A, const ushort* __restrict__ Bt,
    const float* __restrict__ bias0, const float* __restrict__ bias1,
    const float* __restrict__ bias2,
    void* __restrict__ Cout, int M, int N, int K, int nxn)
{
  __shared__ __align__(16) ushort lds[73728];
  const int tid = threadIdx.x;
  const int w = tid >> 6, lane = tid & 63;
  const int lrow = lane & 15, lg = lane >> 4;
  const int wm = w >> 2, wn = w & 3;
  const int cpx = gridDim.x >> 3;
  const int wgid = ((int)blockIdx.x & 7) * cpx + ((int)blockIdx.x >> 3);
  const int mblk = (wgid / nxn) * 128;
  const int nblk = (wgid % nxn) * 256;
  const int NT = K >> 6;

  const int srow = tid >> 3;
  const int scol = 8 * ((tid & 7) ^ (srow & 7));
  const ushort* Abase = A + (size_t)(mblk + srow) * K + scol;
  const ushort* Bbase = Bt + (size_t)(nblk + srow) * K + scol;
  const size_t rstep = (size_t)64 * K;
  const int dA = w * 512;
  const int dB = 8192 + w * 512;

#define STAGE_A(p, bf) { \
    GLDS((p),         &lds[(bf) + dA]); \
    GLDS((p) + rstep, &lds[(bf) + dA + 4096]); }
#define STAGE_B(p, bf) { \
    GLDS((p),             &lds[(bf) + dB]); \
    GLDS((p) + rstep,     &lds[(bf) + dB + 4096]); \
    GLDS((p) + 2 * rstep, &lds[(bf) + dB + 8192]); \
    GLDS((p) + 3 * rstep, &lds[(bf) + dB + 12288]); }

  const int laneA0 = (wm * 64 + lrow) * 64 + ((lg ^ (lrow & 7)) << 3);
  const int laneA1 = (wm * 64 + lrow) * 64 + (((4 + lg) ^ (lrow & 7)) << 3);
  const int laneB0 = 8192 + (wn * 64 + lrow) * 64 + ((lg ^ (lrow & 7)) << 3);
  const int laneB1 = 8192 + (wn * 64 + lrow) * 64 + (((4 + lg) ^ (lrow & 7)) << 3);

  const f32x4 zero = {0.f, 0.f, 0.f, 0.f};
  f32x4 acc[4][4];
#pragma unroll
  for (int m = 0; m < 4; m++)
#pragma unroll
    for (int n = 0; n < 4; n++) acc[m][n] = zero;

  STAGE_A(Abase, 0); STAGE_B(Bbase, 0);
  if (NT > 1) { STAGE_A(Abase + 64, 24576); STAGE_B(Bbase + 64, 24576); }

  const ushort* aP = Abase + 128;
  const ushort* bP = Bbase + 128;
  int bb = 0, bbS = 49152;

  for (int t = 0; t < NT; ++t) {
    if (t < NT - 1) { asm volatile("s_waitcnt vmcnt(6)" ::: "memory"); }
    else            { asm volatile("s_waitcnt vmcnt(0)" ::: "memory"); }
    __builtin_amdgcn_s_barrier();
    const int pA0 = bb + laneA0, pA1 = bb + laneA1;
    const int pB0 = bb + laneB0, pB1 = bb + laneB1;
    const bool pf = (t + 2 < NT);

    if (pf) STAGE_A(aP, bbS);
    {
      s16x8 af[4], bf_[4];
#pragma unroll
      for (int m = 0; m < 4; m++) af[m] = *(const s16x8*)&lds[pA0 + m * 1024];
#pragma unroll
      for (int n = 0; n < 4; n++) bf_[n] = *(const s16x8*)&lds[pB0 + n * 1024];
      __builtin_amdgcn_s_setprio(1);
#pragma unroll
      for (int m = 0; m < 4; m++)
#pragma unroll
        for (int n = 0; n < 4; n++)
          acc[m][n] = __builtin_amdgcn_mfma_f32_16x16x32_bf16(af[m], bf_[n], acc[m][n], 0, 0, 0);
      __builtin_amdgcn_s_setprio(0);
    }
    if (pf) STAGE_B(bP, bbS);
    {
      s16x8 af[4], bf_[4];
#pragma unroll
      for (int m = 0; m < 4; m++) af[m] = *(const s16x8*)&lds[pA1 + m * 1024];
#pragma unroll
      for (int n = 0; n < 4; n++) bf_[n] = *(const s16x8*)&lds[pB1 + n * 1024];
      __builtin_amdgcn_s_setprio(1);
#pragma unroll
      for (int m = 0; m < 4; m++)
#pragma unroll
        for (int n = 0; n < 4; n++)
          acc[m][n] = __builtin_amdgcn_mfma_f32_16x16x32_bf16(af[m], bf_[n], acc[m][n], 0, 0, 0);
      __builtin_amdgcn_s_setprio(0);
    }
    if (pf) { aP += 64; bP += 64; }
    bb  = (bb  == 49152) ? 0 : bb + 24576;
    bbS = (bbS == 49152) ? 0 : bbS + 24576;
  }
#undef STAGE_A
#undef STAGE_B

  float bias_n[4];
#pragma unroll
  for (int n = 0; n < 4; n++) {
    const int col = nblk + wn * 64 + n * 16 + lrow;
    if (bias1) bias_n[n] = (col < 1024) ? bias0[col]
                          : (col < 2048 ? bias1[col - 1024] : bias2[col - 2048]);
    else bias_n[n] = bias0[col];
  }

  __syncthreads();

  if (OUTBF16) {
    ushort* Ct = lds;
#pragma unroll
    for (int m = 0; m < 4; m++)
#pragma unroll
      for (int n = 0; n < 4; n++)
#pragma unroll
        for (int i = 0; i < 4; i++)
          Ct[(wm * 64 + m * 16 + 4 * lg + i) * 256 + wn * 64 + n * 16 + lrow] =
              f2bf(acc[m][n][i] + bias_n[n]);
    __syncthreads();
    ushort* Cg = (ushort*)Cout;
#pragma unroll
    for (int r = 0; r < 8; r++) {
      const int row = r * 16 + (tid >> 5);
      const int col = (tid & 31) * 8;
      *(s16x8*)&Cg[(size_t)(mblk + row) * N + nblk + col] = *(const s16x8*)&lds[r * 4096 + tid * 8];
    }
  } else {
    float* Cf = (float*)lds;
#pragma unroll
    for (int m = 0; m < 4; m++)
#pragma unroll
      for (int n = 0; n < 4; n++)
#pragma unroll
        for (int i = 0; i < 4; i++)
          Cf[(wm * 64 + m * 16 + 4 * lg + i) * 256 + wn * 64 + n * 16 + lrow] =
              acc[m][n][i] + bias_n[n];
    __syncthreads();
    float* Cg = (float*)Cout;
#pragma unroll
    for (int r = 0; r < 16; r++) {
      const int row = r * 8 + (tid >> 6);
      const int col = (tid & 63) * 4;
      *(float4*)&Cg[(size_t)(mblk + row) * N + nblk + col] = *(const float4*)&Cf[r * 2048 + tid * 4];
    }
  }
}

// ---------------- attention: 128-q blocks, 4 waves share K/V tiles (r14 best) ----------------
__global__ __launch_bounds__(256, 2) void attn_kernel(const ushort* __restrict__ qkv,
                                                      ushort* __restrict__ outp,
                                                      float* __restrict__ oPart,
                                                      float* __restrict__ mPart,
                                                      float* __restrict__ lPart)
{
  __shared__ __align__(16) ushort Ks[2][4096];
  __shared__ __align__(16) ushort Vt[2][4096];

  const int tid = threadIdx.x;
  const int w = tid >> 6, lane = tid & 63;
  const int lq = lane & 31, hi = lane >> 5;
  const float NINF = -__builtin_inff();

  const int bid = (blockIdx.x & 7) * 184 + (blockIdx.x >> 3);
  int h, b, bx, kv_lo, kv_hi, chunk = 0;
  bool isGlobal;
  if (bid < 512) {
    isGlobal = true; h = 0;
    chunk = bid >> 6;
    int qb = bid & 63;
    b = qb >> 4; bx = qb & 15;
    kv_lo = chunk * 256; kv_hi = kv_lo + 256;
  } else {
    isGlobal = false;
    int t = bid - 512;
    h = 1 + (t >> 6);
    int qb = t & 63;
    b = qb >> 4; bx = qb & 15;
    kv_lo = bx * 128 - 128; if (kv_lo < 0) kv_lo = 0;
    kv_hi = bx * 128 + 256; if (kv_hi > 2048) kv_hi = 2048;
  }
  const int q0blk = bx * 128;
  const int qw = q0blk + 32 * w;
  const int q_abs = qw + lq;
  const ushort* Qp = qkv + (size_t)b * 2048 * 3072 + h * 64;
  const ushort* Kp = Qp + 1024;
  const ushort* Vp = Qp + 2048;

  s16x8 qf[4];
#pragma unroll
  for (int c = 0; c < 4; c++)
    qf[c] = *(const s16x8*)(Qp + (size_t)q_abs * 3072 + 16 * c + 8 * hi);

  f32x16 o0, o1;
#pragma unroll
  for (int r = 0; r < 16; r++) { o0[r] = 0.f; o1[r] = 0.f; }
  float mrun = -3e38f, lsum = 0.f;
  const float SCL = 0.18033688011112042f;  // 1/8 * log2(e)

  const int kg = lane >> 3;
  const int kswz = 8 * ((lane & 7) ^ kg);
  const int krow0 = 16 * w + kg;
  const int vsp = tid >> 3;
  const int vsg = tid & 7;

  const ushort* vr0 = Vp + (size_t)(kv_lo + 2 * vsp) * 3072 + 8 * vsg;
  s16x8 v0 = *(const s16x8*)vr0;
  s16x8 v1 = *(const s16x8*)(vr0 + 3072);
  GLDS(Kp + (size_t)(kv_lo + krow0) * 3072 + kswz,     &Ks[0][(2 * w) * 512]);
  GLDS(Kp + (size_t)(kv_lo + krow0 + 8) * 3072 + kswz, &Ks[0][(2 * w + 1) * 512]);

  int buf = 0;
  for (int kv = kv_lo; kv < kv_hi; kv += 64) {
    const bool hasNext = (kv + 64 < kv_hi);
    const bool active = isGlobal || ((kv + 63 >= qw - 128) && (kv <= qw + 159));
    const bool needMask = !isGlobal && active && ((kv < qw - 97) || (kv > qw + 65));

    s16x8 vn0, vn1;
    if (hasNext) {
      const ushort* vr = Vp + (size_t)(kv + 64 + 2 * vsp) * 3072 + 8 * vsg;
      vn0 = *(const s16x8*)vr;
      vn1 = *(const s16x8*)(vr + 3072);
    }

#pragma unroll
    for (int j = 0; j < 8; j++) {
      const int d = 8 * vsg + j;
      const int sl = ((vsp >> 2) ^ j ^ vsg) & 7;
      *(uint*)&Vt[buf][d * 64 + sl * 8 + ((2 * vsp) & 7)] =
          (uint)(ushort)v0[j] | ((uint)(ushort)v1[j] << 16);
    }
    if (hasNext) asm volatile("s_waitcnt vmcnt(2)" ::: "memory");
    else         asm volatile("s_waitcnt vmcnt(0)" ::: "memory");
    asm volatile("s_waitcnt lgkmcnt(0)" ::: "memory");
    __builtin_amdgcn_s_barrier();
    if (hasNext) {
      GLDS(Kp + (size_t)(kv + 64 + krow0) * 3072 + kswz,     &Ks[buf ^ 1][(2 * w) * 512]);
      GLDS(Kp + (size_t)(kv + 64 + krow0 + 8) * 3072 + kswz, &Ks[buf ^ 1][(2 * w + 1) * 512]);
    }

    if (active) {
      f32x16 s0, s1;
#pragma unroll
      for (int r = 0; r < 16; r++) { s0[r] = 0.f; s1[r] = 0.f; }
#pragma unroll
      for (int c = 0; c < 4; c++) {
        const int gx = ((2 * c + hi) ^ (lq & 7)) << 3;
        s16x8 kf0 = *(const s16x8*)&Ks[buf][lq * 64 + gx];
        s16x8 kf1 = *(const s16x8*)&Ks[buf][(32 + lq) * 64 + gx];
        s0 = __builtin_amdgcn_mfma_f32_32x32x16_bf16(kf0, qf[c], s0, 0, 0, 0);
        s1 = __builtin_amdgcn_mfma_f32_32x32x16_bf16(kf1, qf[c], s1, 0, 0, 0);
      }

      float rm = NINF;
      if (needMask) {
#pragma unroll
        for (int r = 0; r < 16; r++) {
          const int kvr = kv + (r & 3) + 8 * (r >> 2) + 4 * hi;
          const int dq0 = q_abs - kvr;
          s0[r] = (dq0 <= 128 && dq0 >= -128) ? s0[r] : NINF;
          const int dq1 = dq0 - 32;
          s1[r] = (dq1 <= 128 && dq1 >= -128) ? s1[r] : NINF;
          rm = fmaxf(rm, fmaxf(s0[r], s1[r]));
        }
      } else {
#pragma unroll
        for (int r = 0; r < 16; r++) rm = fmaxf(rm, fmaxf(s0[r], s1[r]));
      }
      rm = fmaxf(rm, __shfl_xor(rm, 32)) * SCL;

      if (!__all(rm <= mrun + 8.f)) {
        float mnew = fmaxf(mrun, rm);
        float alpha = fexp2(mrun - mnew);
        mrun = mnew;
        lsum *= alpha;
#pragma unroll
        for (int r = 0; r < 16; r++) {
          float av = __shfl(alpha, (r & 3) + 8 * (r >> 2) + 4 * hi);
          o0[r] *= av; o1[r] *= av;
        }
      }

      float rs = 0.f;
#pragma unroll
      for (int r = 0; r < 16; r++) {
        s0[r] = fexp2(__builtin_fmaf(s0[r], SCL, -mrun)); rs += s0[r];
        s1[r] = fexp2(__builtin_fmaf(s1[r], SCL, -mrun)); rs += s1[r];
      }
      rs += __shfl_xor(rs, 32);
      lsum += rs;

#pragma unroll
      for (int cc = 0; cc < 4; cc++) {
        uint x0, x1, x2, x3;
        if (cc == 0) { x0 = cvtpk(s0[0], s0[1]);  x1 = cvtpk(s0[2], s0[3]);
                       x2 = cvtpk(s0[4], s0[5]);  x3 = cvtpk(s0[6], s0[7]); }
        else if (cc == 1) { x0 = cvtpk(s0[8], s0[9]);   x1 = cvtpk(s0[10], s0[11]);
                            x2 = cvtpk(s0[12], s0[13]); x3 = cvtpk(s0[14], s0[15]); }
        else if (cc == 2) { x0 = cvtpk(s1[0], s1[1]);  x1 = cvtpk(s1[2], s1[3]);
                            x2 = cvtpk(s1[4], s1[5]);  x3 = cvtpk(s1[6], s1[7]); }
        else { x0 = cvtpk(s1[8], s1[9]);   x1 = cvtpk(s1[10], s1[11]);
               x2 = cvtpk(s1[12], s1[13]); x3 = cvtpk(s1[14], s1[15]); }
        uint t0 = hi ? x0 : x2;
        uint t1 = hi ? x1 : x3;
        uint r0 = __shfl_xor(t0, 32);
        uint r1 = __shfl_xor(t1, 32);
        uint w0 = hi ? r0 : x0;
        uint w1 = hi ? r1 : x1;
        uint w2 = hi ? x2 : r0;
        uint w3 = hi ? x3 : r1;
        s16x8 pa = mk_frag(w0, w1, w2, w3);
#pragma unroll
        for (int db = 0; db < 2; db++) {
          const int d = 32 * db + lq;
          s16x8 vf = *(const s16x8*)&Vt[buf][d * 64 +
              ((((2 * cc + hi) ^ (d & 7) ^ (d >> 3)) & 7) << 3)];
          if (db == 0) o0 = __builtin_amdgcn_mfma_f32_32x32x16_bf16(pa, vf, o0, 0, 0, 0);
          else         o1 = __builtin_amdgcn_mfma_f32_32x32x16_bf16(pa, vf, o1, 0, 0, 0);
        }
      }
    }

    v0 = vn0; v1 = vn1;
    buf ^= 1;
  }

  if (isGlobal) {
    const size_t rq = (size_t)(chunk * 4 + b) * 2048 + qw;
    if (hi == 0) {
      mPart[rq + lq] = mrun;
      lPart[rq + lq] = lsum;
    }
#pragma unroll
    for (int r = 0; r < 16; r++) {
      const int qr = (r & 3) + 8 * (r >> 2) + 4 * hi;
      oPart[(rq + qr) * 64 + lq]      = o0[r];
      oPart[(rq + qr) * 64 + 32 + lq] = o1[r];
    }
  } else {
    float linv = 1.f / lsum;
#pragma unroll
    for (int r = 0; r < 16; r++) {
      const int qr = (r & 3) + 8 * (r >> 2) + 4 * hi;
      float iv = __shfl(linv, qr);
      size_t orow = (size_t)(b * 2048 + qw + qr) * 1024 + h * 64;
      outp[orow + lq]      = f2bf(o0[r] * iv);
      outp[orow + 32 + lq] = f2bf(o1[r] * iv);
    }
  }
}

// ---------------- combine global-head partials ----------------
__global__ __launch_bounds__(256) void combine_kernel(const float* __restrict__ oPart,
                                                      const float* __restrict__ mPart,
                                                      const float* __restrict__ lPart,
                                                      ushort* __restrict__ attno) {
  const int tid = threadIdx.x;
  const int row = blockIdx.x * 64 + (tid >> 2);
  const int d0 = (tid & 3) * 16;
  float m[8], l[8], M = -3e38f;
#pragma unroll
  for (int p = 0; p < 8; p++) {
    m[p] = mPart[p * 8192 + row];
    l[p] = lPart[p * 8192 + row];
    M = fmaxf(M, m[p]);
  }
  float L = 0.f, wgt[8];
#pragma unroll
  for (int p = 0; p < 8; p++) { wgt[p] = fexp2(m[p] - M); L += wgt[p] * l[p]; }
  float inv = 1.f / L;
  float acc[16];
#pragma unroll
  for (int j = 0; j < 16; j++) acc[j] = 0.f;
#pragma unroll
  for (int p = 0; p < 8; p++) {
    const float* op = oPart + ((size_t)p * 8192 + row) * 64 + d0;
    float wv = wgt[p];
#pragma unroll
    for (int j = 0; j < 16; j += 4) {
      float4 v = *(const float4*)(op + j);
      acc[j]     += wv * v.x; acc[j + 1] += wv * v.y;
      acc[j + 2] += wv * v.z; acc[j + 3] += wv * v.w;
    }
  }
  ushort* dst = attno + (size_t)row * 1024 + d0;
#pragma unroll
  for (int j = 0; j < 16; j++) dst[j] = f2bf(acc[j] * inv);
}

// ---------------- launch ----------------
extern "C" void kernel_launch(void* const* d_in, const int* in_sizes, int n_in,
                              void* d_out, int out_size, void* d_ws, size_t ws_size,
                              hipStream_t stream) {
  const float* x  = (const float*)d_in[0];
  const float* wq = (const float*)d_in[1];
  const float* bq = (const float*)d_in[2];
  const float* wk = (const float*)d_in[3];
  const float* bk = (const float*)d_in[4];
  const float* wv = (const float*)d_in[5];
  const float* bv = (const float*)d_in[6];
  const float* wo = (const float*)d_in[7];
  const float* bo = (const float*)d_in[8];

  char* ws = (char*)d_ws;
  ushort* xb    = (ushort*)(ws);                 // 8192x1024 bf16 = 16 MB
  ushort* wqkvb = (ushort*)(ws + 16777216);      // 3072x1024 bf16 =  6 MB
  ushort* wob   = (ushort*)(ws + 23068672);      // 1024x1024 bf16 =  2 MB
  ushort* qkvb  = (ushort*)(ws + 25165824);      // 8192x3072 bf16 = 48 MB
  ushort* attno = (ushort*)(ws + 75497472);      // 8192x1024 bf16 = 16 MB
  float* oPart = (float*)(ws);                   // 8x8192x64 f32 = 16 MB (over xb)
  float* mPart = (float*)(ws + 16777216);
  float* lPart = (float*)(ws + 16777216 + 262144);

  castall<<<12288, 256, 0, stream>>>(x, wq, wk, wv, wo, xb, wqkvb, wob);

  gemm256<1><<<768, 512, 0, stream>>>(xb, wqkvb, bq, bk, bv,
                                      (void*)qkvb, 8192, 3072, 1024, 12);

  attn_kernel<<<1472, 256, 0, stream>>>(qkvb, attno, oPart, mPart, lPart);
  combine_kernel<<<128, 256, 0, stream>>>(oPart, mPart, lPart, attno);

  gemm256<0><<<256, 512, 0, stream>>>(attno, wob, bo, nullptr, nullptr,
                                      (void*)d_out, 8192, 1024, 1024, 4);
}